// Round 16
// baseline (797.948 us; speedup 1.0000x reference)
//
#include <hip/hip_runtime.h>
#include <hip/hip_bf16.h>
#include <math.h>
#include <string.h>
#include <stdint.h>

#define NN 8192
#define EE 131072

#define PI_F     3.14159265358979323846f
#define SQRT3_F  1.7320508075688772f
#define INV_SQ2  0.7071067811865476f
#define INV_SQ3  0.5773502691896258f
#define INV_S32  0.17677669529663687f
#define INV_S96  0.10206207261596575f
#define INV_S10  0.31622776601683794f
#define C_S_F    0.3826834323650898f
#define C_X_F    0.9238795325112867f
#define EMB_S    2.8234621965789795f   /* sqrt(10)/1.12 */
#define OUT_S    0.044194173824159216f /* 1/sqrt(512)   */

typedef unsigned int uint;
typedef unsigned short ushort;
typedef unsigned long long u64;
typedef __attribute__((ext_vector_type(8))) short short8;
typedef __attribute__((ext_vector_type(4))) float float4v;

__device__ __forceinline__ float sigmoid_f(float x){ return 1.0f/(1.0f+__expf(-x)); }
__device__ __forceinline__ ushort f2bf(float f){
    uint u = __float_as_uint(f);
    u = (u + 0x7fffu + ((u>>16)&1u)) >> 16;
    return (ushort)u;
}
__device__ __forceinline__ float bf2f(ushort w){ return __uint_as_float(((uint)w)<<16); }
__device__ __forceinline__ uint pk2bf(float a, float b){
    __hip_bfloat162 h = __float22bfloat162_rn(make_float2(a,b));   // v_cvt_pk_bf16_f32 (RNE)
    uint u; memcpy(&u,&h,4); return u;
}

// ---------------- CSR build (sort edges by dst) ----------------
__global__ __launch_bounds__(256) void k_count(const int* __restrict__ dst, int* __restrict__ cnt)
{
    int e = blockIdx.x*256 + threadIdx.x;
    atomicAdd(&cnt[dst[e]], 1);
}

__global__ __launch_bounds__(1024) void k_scan(const int* __restrict__ cnt,
    int* __restrict__ off, int* __restrict__ cur)
{
    __shared__ int partial[1024];
    int t = threadIdx.x;
    int base = t*8;
    int local[8];
    int s = 0;
    #pragma unroll
    for(int i=0;i<8;i++){ local[i]=s; s += cnt[base+i]; }
    partial[t] = s;
    __syncthreads();
    for(int d=1; d<1024; d<<=1){
        int v = (t>=d) ? partial[t-d] : 0;
        __syncthreads();
        partial[t] += v;
        __syncthreads();
    }
    int pref = (t>0) ? partial[t-1] : 0;
    #pragma unroll
    for(int i=0;i<8;i++){
        int o = pref + local[i];
        off[base+i] = o; cur[base+i] = o;
    }
    if (t==1023) off[NN] = partial[1023];
}

__global__ __launch_bounds__(256) void k_scatter(const int* __restrict__ dst,
    int* __restrict__ cur, int* __restrict__ eids)
{
    int e = blockIdx.x*256 + threadIdx.x;
    int p = atomicAdd(&cur[dst[e]], 1);
    eids[p] = e;
}

// ---------------- edge geometry in CSR-sorted order; ygeo = (y0, y1x, y1y, y1z) float4 ----------
__global__ __launch_bounds__(256) void k_geom_sorted(const float* __restrict__ ev,
    const int* __restrict__ eids, const int* __restrict__ esrc,
    const int* __restrict__ edst, const int* __restrict__ batch,
    float4* __restrict__ ygeo, float* __restrict__ embs,
    int* __restrict__ esrcs, int* __restrict__ gbs)
{
    int p = blockIdx.x*256 + threadIdx.x;
    int e = eids[p];
    float vx=ev[e*3+0], vy=ev[e*3+1], vz=ev[e*3+2];
    float r = sqrtf(vx*vx+vy*vy+vz*vz);
    float uu = 0.5f*r - 2.0f;                 // u = 2*(r/4 - 1)
    float cut;
    if (uu > 0.0f)       cut = 0.0f;
    else if (uu < -1.0f) cut = 1.0f;
    else                 cut = 0.5f*(1.0f - cosf(PI_F*uu));
    float s = SQRT3_F*cut/(r + 1e-12f);
    ygeo[p] = make_float4(cut, vx*s, vy*s, vz*s);
    #pragma unroll
    for(int b=0;b<10;b++){
        float d = r*2.25f - (float)b;         // (r - b*4/9)/(4/9)
        embs[p*10+b] = __expf(-d*d)*EMB_S;
    }
    esrcs[p] = esrc[e];
    gbs[p]   = batch[edst[e]];
}

// ---------------- per-node input linears -> PACKED bf16 A planes ----------------
// Abf row (128 uints): q*32+u = bf16 pair (plane 2q, plane 2q+1) of channel u.
// Planes: 0=a_so 1=a_se 2=vo_x 3=vo_y 4=vo_z 5=ve_x 6=ve_y 7=ve_z.
__global__ __launch_bounds__(256) void k_lin1(const float* __restrict__ st,
    const float* __restrict__ w_so, const float* __restrict__ w_se,
    const float* __restrict__ w_vo, const float* __restrict__ w_ve,
    uint* __restrict__ Abf)
{
    __shared__ float wl[4][1024];
    __shared__ float sl[8][256];
    __shared__ float ol[8][256];
    int t = threadIdx.x;
    for(int i=t;i<1024;i+=256){ wl[0][i]=w_so[i]; wl[1][i]=w_se[i]; wl[2][i]=w_vo[i]; wl[3][i]=w_ve[i]; }
    int n0 = blockIdx.x*8;
    for(int i=t;i<2048;i+=256){ int k=i>>8, c=i&255; sl[k][c]=st[(n0+k)*256+c]; }
    __syncthreads();
    for(int k=0;k<8;k++){
        float acc = 0.0f;
        if (t < 64){
            int m = t>>5, v = t&31;
            const float* w = wl[m];
            const float* s = &sl[k][m*32];
            #pragma unroll
            for(int u=0;u<32;u++) acc += s[u]*w[u*32+v];
        } else if (t < 160){
            int idx=t-64, i=idx>>5, v=idx&31;
            #pragma unroll
            for(int u=0;u<32;u++) acc += sl[k][64+u*3+i]*wl[2][u*32+v];
        } else {
            int idx=t-160, i=idx>>5, v=idx&31;
            #pragma unroll
            for(int u=0;u<32;u++) acc += sl[k][160+u*3+i]*wl[3][u*32+v];
        }
        ol[k][t] = acc * INV_S32;
    }
    __syncthreads();
    for(int idx=t; idx<1024; idx+=256){
        int k = idx>>7, j = idx&127, q = j>>5, u = j&31;
        Abf[(size_t)(n0+k)*128 + j] = pk2bf(ol[k][q*64 + u], ol[k][q*64 + 32 + u]);
    }
}

// ---------------- rw2 fp32 -> bf16 fragment layout, PLANE-MAJOR packed order ----------
__global__ __launch_bounds__(256) void k_prep3(const float* __restrict__ rw2, ushort* __restrict__ Bfrag)
{
    int L = blockIdx.x / 160;
    int idx = (blockIdx.x % 160)*256 + threadIdx.x;      // over 128*320 elements
    int j = idx & 7;
    int l = (idx>>3) & 63;
    int rest = idx >> 9;                          // ks*20 + mt
    int nt = rest % 20;
    int ks = rest / 20;
    int k = ks*32 + ((l>>4)&3)*8 + j;
    int p = nt*16 + (l&15);
    int n = (2*(p>>6) + (p&1))*32 + ((p&63)>>1);  // plane-major packing
    float v = (k < 100) ? rw2[L*32000 + k*320 + n] : 0.0f;
    Bfrag[L*40960 + idx] = f2bf(v);
}

__global__ __launch_bounds__(256) void k_prep64(const float* __restrict__ rw2, ushort* __restrict__ Bfrag)
{
    int idx = blockIdx.x*256 + threadIdx.x;      // over 128*64 elements
    int j = idx & 7;
    int l = (idx>>3) & 63;
    int rest = idx >> 9;                          // ks*4 + mt
    int nt = rest % 4;
    int ks = rest / 4;
    int k = ks*32 + ((l>>4)&3)*8 + j;
    int p = nt*16 + (l&15);
    int n = (p % 2)*32 + p/2;
    float v = (k < 100) ? rw2[k*64 + n] : 0.0f;
    Bfrag[idx] = f2bf(v);
}

// ---------------- update-weight pre-pack: scales folded, dense, all 3 layers ----------------
__global__ __launch_bounds__(256) void k_prepu(
    const float* __restrict__ sc_so, const float* __restrict__ sc_se,
    const float* __restrict__ sc_vo, const float* __restrict__ sc_ve,
    const float* __restrict__ lin2_so, const float* __restrict__ lin2_se,
    const float* __restrict__ lin2_vo, const float* __restrict__ lin2_ve,
    float* __restrict__ Wcat0, float* __restrict__ Wcat1)
{
    int idx = blockIdx.x*256 + threadIdx.x;   // 3 layers x 20480
    int L = idx / 20480;
    int k = idx % 20480;
    const float CS32 = C_S_F*INV_S32, CX8 = C_X_F*0.125f, CX96 = C_X_F*INV_S96;
    if (k < 12288){
        int r = k >> 7, c = k & 127;
        float v;
        if (c < 32) v = (r<32) ? CS32*sc_so[L*1024 + r*32+c]        : CX8*lin2_so[L*2048 + (r-32)*32+c];
        else        v = (r<32) ? CS32*sc_se[L*3072 + r*96+(c-32)]   : CX8*lin2_se[L*6144 + (r-32)*96+(c-32)];
        Wcat0[L*12288 + k] = v;
    } else {
        int k2 = k - 12288;
        int r = k2 >> 6, c = k2 & 63;
        float v;
        if (c < 32) v = (r<32) ? CS32*sc_vo[L*1024 + r*32+c]        : CX96*lin2_vo[L*3072 + (r-32)*32+c];
        else        v = (r<32) ? CS32*sc_ve[L*1024 + r*32+(c-32)]   : CX96*lin2_ve[L*3072 + (r-32)*32+(c-32)];
        Wcat1[L*8192 + k2] = v;
    }
}

// ---------------- FUSED radial+aggregate: 3 nodes/block, W never touches HBM ----------------
// Per <=64-edge chunk: phase1 h (uniform rw1) -> MFMA (C[pos x edge] = RW2^T @ H^T) ->
// plane-major C-stage in LDS -> waves 0..2 aggregate their node's chunk edges from LDS.
// Accumulators persist in registers across chunks; one nbuf write per node. No atomics.
__global__ __launch_bounds__(256, 3) void k_radagg(const float* __restrict__ emb,
    const float* __restrict__ rw1, const ushort* __restrict__ Afrag,
    const uint* __restrict__ Abf, const float4* __restrict__ ygeo,
    const int* __restrict__ off, const int* __restrict__ esrcs,
    float* __restrict__ nbuf)
{
    constexpr int NCOL = 320, MTW = 5, STR = NCOL + 8;   // 328 ushorts/row
    __shared__ __align__(16) ushort s_big[64*STR];       // h-frag (first 16KB) then C-stage, 41KB
    __shared__ float s_emb[640];
    int t = threadIdx.x, w = t >> 6, l = t & 63;
    int u = l & 31, half = l >> 5;
    int n0 = blockIdx.x*3;
    int ebase = off[n0];
    int nlast = (n0+3 < NN) ? n0+3 : NN;
    int eend_all = off[nlast];
    int my_n = n0 + w;
    bool active_node = (w < 3) && (my_n < NN);
    int nlo = active_node ? off[my_n]   : 0;
    int nhi = active_node ? off[my_n+1] : 0;

    float a_n0o0=0.f, a_n0o1=0.f, a_n0e0=0.f, a_n0e1=0.f;
    float a1o[3][3] = {{0}}, a1e[3][3] = {{0}};

    for (int ebeg = ebase; ebeg < eend_all; ebeg += 64){
        int valid = eend_all - ebeg; if (valid > 64) valid = 64;
        __syncthreads();                       // guard prev chunk's C-stage reads
        // zero h-frag (4096 uints) + load emb chunk
        for(int i=t;i<4096;i+=256) ((uint*)s_big)[i] = 0u;
        for(int i=t;i<valid*10;i+=256) s_emb[i] = emb[(size_t)ebeg*10 + i];
        __syncthreads();
        {   // phase 1: lane = edge, wave = k-slice (SGPR-uniform rw1)
            int w4 = __builtin_amdgcn_readfirstlane(t) >> 6;
            if (l < valid){
                float ev[10];
                #pragma unroll
                for(int r=0;r<10;r++) ev[r] = s_emb[l*10 + r];
                int m = l & 15, nt = l >> 4;
                int kbeg = w4*25;
                #pragma unroll 5
                for(int k=kbeg; k<kbeg+25; k++){
                    float a0 = 0.0f;
                    #pragma unroll
                    for(int r=0;r<10;r++) a0 += ev[r]*rw1[r*100 + k];
                    a0 *= INV_S10;
                    float h = a0*sigmoid_f(a0);
                    int ks = k >> 5, kk = k & 31;
                    int lt = m | ((kk>>3)<<4);
                    s_big[((ks*4 + nt)*64 + lt)*8 + (kk&7)] = f2bf(h);
                }
            }
        }
        __syncthreads();
        // phase 2: MFMA
        float4v acc[MTW][4];
        #pragma unroll
        for(int a=0;a<MTW;a++)
            #pragma unroll
            for(int b=0;b<4;b++)
                acc[a][b] = (float4v){0.f,0.f,0.f,0.f};
        #pragma unroll
        for(int ks=0;ks<4;ks++){
            short8 bfr[4];
            #pragma unroll
            for(int nt=0;nt<4;nt++)
                bfr[nt] = *((const short8*)&s_big[((ks*4+nt)*64 + l)*8]);
            #pragma unroll
            for(int mtl=0;mtl<MTW;mtl++){
                short8 af = *((const short8*)(Afrag + ((size_t)(ks*(NCOL/16) + w*MTW + mtl)*64 + l)*8));
                #pragma unroll
                for(int nt=0;nt<4;nt++)
                    acc[mtl][nt] = __builtin_amdgcn_mfma_f32_16x16x32_bf16(af, bfr[nt], acc[mtl][nt], 0, 0, 0);
            }
        }
        __syncthreads();   // h-frag reads done; reuse s_big as C-stage
        {
            int col16 = l & 15, rquad = l >> 4;
            #pragma unroll
            for(int mtl=0;mtl<MTW;mtl++){
                int pos0 = (w*MTW + mtl)*16 + rquad*4;
                #pragma unroll
                for(int nt=0;nt<4;nt++){
                    int edge = nt*16 + col16;
                    uint u01 = pk2bf(acc[mtl][nt][0]*0.1f, acc[mtl][nt][1]*0.1f);
                    uint u23 = pk2bf(acc[mtl][nt][2]*0.1f, acc[mtl][nt][3]*0.1f);
                    u64 pk = (u64)u01 | ((u64)u23 << 32);
                    *((u64*)&s_big[edge*STR + pos0]) = pk;
                }
            }
        }
        __syncthreads();
        // phase 3: aggregate this chunk's edges of my node from the LDS C-stage
        if (active_node){
            int lo = (nlo > ebeg) ? nlo : ebeg;
            int hi = (nhi < ebeg+valid) ? nhi : ebeg+valid;
            for(int p = lo + half; p < hi; p += 2){
                int eloc = p - ebeg;
                int s = esrcs[p];
                float4 yg = ygeo[p];
                float cy0 = yg.x, v1x = yg.y, v1y = yg.z, v1z = yg.w;
                const uint* Au = Abf + (size_t)s*128;
                uint a01=Au[u], a23=Au[32+u], a45=Au[64+u], a67=Au[96+u];
                float aso=bf2f((ushort)a01), ase=bf2f((ushort)(a01>>16));
                float vox=bf2f((ushort)a23), voy=bf2f((ushort)(a23>>16));
                float voz=bf2f((ushort)a45), vex=bf2f((ushort)(a45>>16));
                float vey=bf2f((ushort)a67), vez=bf2f((ushort)(a67>>16));
                const uint* Wu = (const uint*)(s_big + eloc*STR);
                uint p01=Wu[u], p23=Wu[32+u], p45=Wu[64+u], p67=Wu[96+u], p89=Wu[128+u];
                float w0=bf2f((ushort)p01), w1=bf2f((ushort)(p01>>16));
                float w2=bf2f((ushort)p23), w3=bf2f((ushort)(p23>>16));
                float w4=bf2f((ushort)p45), w5=bf2f((ushort)(p45>>16));
                float w6=bf2f((ushort)p67), w7=bf2f((ushort)(p67>>16));
                float w8=bf2f((ushort)p89), w9=bf2f((ushort)(p89>>16));
                float dve = (vex*v1x+vey*v1y+vez*v1z)*INV_SQ3;
                float dvo = (vox*v1x+voy*v1y+voz*v1z)*INV_SQ3;
                float cvex=(vey*v1z-vez*v1y)*INV_SQ2, cvey=(vez*v1x-vex*v1z)*INV_SQ2, cvez=(vex*v1y-vey*v1x)*INV_SQ2;
                float cvox=(voy*v1z-voz*v1y)*INV_SQ2, cvoy=(voz*v1x-vox*v1z)*INV_SQ2, cvoz=(vox*v1y-voy*v1x)*INV_SQ2;
                a_n0o0 += w0*aso*cy0;
                a_n0o1 += w1*dve;
                a_n0e0 += w2*ase*cy0;
                a_n0e1 += w3*dvo;
                a1o[0][0]+=w4*ase*v1x; a1o[0][1]+=w4*ase*v1y; a1o[0][2]+=w4*ase*v1z;
                a1o[1][0]+=w5*vox*cy0; a1o[1][1]+=w5*voy*cy0; a1o[1][2]+=w5*voz*cy0;
                a1o[2][0]+=w6*cvex;    a1o[2][1]+=w6*cvey;    a1o[2][2]+=w6*cvez;
                a1e[0][0]+=w7*aso*v1x; a1e[0][1]+=w7*aso*v1y; a1e[0][2]+=w7*aso*v1z;
                a1e[1][0]+=w8*cvox;    a1e[1][1]+=w8*cvoy;    a1e[1][2]+=w8*cvoz;
                a1e[2][0]+=w9*vex*cy0; a1e[2][1]+=w9*vey*cy0; a1e[2][2]+=w9*vez*cy0;
            }
        }
    }
    // combine halves + write nbuf (per active node wave)
    a_n0o0 += __shfl_xor(a_n0o0, 32);
    a_n0o1 += __shfl_xor(a_n0o1, 32);
    a_n0e0 += __shfl_xor(a_n0e0, 32);
    a_n0e1 += __shfl_xor(a_n0e1, 32);
    #pragma unroll
    for(int sp=0;sp<3;sp++)
        #pragma unroll
        for(int i=0;i<3;i++){
            a1o[sp][i] += __shfl_xor(a1o[sp][i], 32);
            a1e[sp][i] += __shfl_xor(a1e[sp][i], 32);
        }
    if (active_node){
        float s0 = INV_SQ2*0.25f;
        float s1 = INV_SQ3*0.25f;
        float* nb = nbuf + (size_t)my_n*704;
        if (half==0){
            nb[u]      = a_n0o0*s0;
            nb[32+u]   = a_n0o1*s0;
            nb[64+u]   = a_n0e0*s0;
            nb[96+u]   = a_n0e1*s0;
            #pragma unroll
            for(int sp=0;sp<3;sp++)
                #pragma unroll
                for(int i=0;i<3;i++)
                    nb[128 + i*96 + sp*32 + u] = a1o[sp][i]*s1;
        } else {
            #pragma unroll
            for(int sp=0;sp<3;sp++)
                #pragma unroll
                for(int i=0;i<3;i++)
                    nb[416 + i*96 + sp*32 + u] = a1e[sp][i]*s1;
        }
    }
}

// ---------------- radial MLP via MFMA (final layer only, NCOL=64) ----------
template<int NCOL>
__global__ __launch_bounds__(256, 3) void k_radial_mfma(const float* __restrict__ emb,
    const float* __restrict__ rw1, const ushort* __restrict__ Afrag,
    ushort* __restrict__ Wout)
{
    constexpr int MTW = NCOL/64;
    constexpr int STR = NCOL + 8;
    constexpr int BIG = (64*STR > 8192) ? 64*STR : 8192;
    __shared__ __align__(16) ushort s_big[BIG];
    __shared__ float s_emb[640];
    int t = threadIdx.x;
    int ebase = blockIdx.x*64;
    for(int i=t;i<640;i+=256)  s_emb[i] = emb[ebase*10 + i];
    for(int i=t;i<1024;i+=256) ((uint*)s_big)[3072 + i] = 0u;
    __syncthreads();
    {
        int w4 = __builtin_amdgcn_readfirstlane(t) >> 6;
        int l = t & 63;
        float ev[10];
        #pragma unroll
        for(int r=0;r<10;r++) ev[r] = s_emb[l*10 + r];
        int m  = l & 15, nt = l >> 4;
        int kbeg = w4*25;
        #pragma unroll 5
        for(int k=kbeg; k<kbeg+25; k++){
            float a0 = 0.0f;
            #pragma unroll
            for(int r=0;r<10;r++) a0 += ev[r]*rw1[r*100 + k];
            a0 *= INV_S10;
            float h = a0*sigmoid_f(a0);
            int ks = k >> 5, kk = k & 31;
            int lt = m | ((kk>>3)<<4);
            s_big[((ks*4 + nt)*64 + lt)*8 + (kk&7)] = f2bf(h);
        }
    }
    __syncthreads();
    int w = t >> 6, l = t & 63;
    float4v acc[MTW][4];
    #pragma unroll
    for(int a=0;a<MTW;a++)
        #pragma unroll
        for(int b=0;b<4;b++)
            acc[a][b] = (float4v){0.f,0.f,0.f,0.f};
    #pragma unroll
    for(int ks=0;ks<4;ks++){
        short8 bfr[4];
        #pragma unroll
        for(int nt=0;nt<4;nt++)
            bfr[nt] = *((const short8*)&s_big[((ks*4+nt)*64 + l)*8]);
        #pragma unroll
        for(int mtl=0;mtl<MTW;mtl++){
            short8 af = *((const short8*)(Afrag + ((size_t)(ks*(NCOL/16) + w*MTW + mtl)*64 + l)*8));
            #pragma unroll
            for(int nt=0;nt<4;nt++)
                acc[mtl][nt] = __builtin_amdgcn_mfma_f32_16x16x32_bf16(af, bfr[nt], acc[mtl][nt], 0, 0, 0);
        }
    }
    __syncthreads();
    {
        int col16 = l & 15, rquad = l >> 4;
        #pragma unroll
        for(int mtl=0;mtl<MTW;mtl++){
            int pos0 = (w*MTW + mtl)*16 + rquad*4;
            #pragma unroll
            for(int nt=0;nt<4;nt++){
                int edge = nt*16 + col16;
                uint u01 = pk2bf(acc[mtl][nt][0]*0.1f, acc[mtl][nt][1]*0.1f);
                uint u23 = pk2bf(acc[mtl][nt][2]*0.1f, acc[mtl][nt][3]*0.1f);
                u64 pk = (u64)u01 | ((u64)u23 << 32);
                *((u64*)&s_big[edge*STR + pos0]) = pk;
            }
        }
    }
    __syncthreads();
    for (int idx = t; idx < 64*(NCOL/8); idx += 256){
        int row = idx/(NCOL/8), o8 = idx%(NCOL/8);
        short8 vv = *((const short8*)&s_big[row*STR + o8*8]);
        *((short8*)(Wout + (size_t)(ebase+row)*NCOL + o8*8)) = vv;
    }
}

// ---------------- node update: 8 nodes/block, LDS-transposed inputs, packed weights ---
__global__ __launch_bounds__(256, 4) void k_update(const float* __restrict__ st,
    const float* __restrict__ nbuf, const float* __restrict__ W0,
    const float* __restrict__ W1, float* __restrict__ stnew)
{
    __shared__ float X0T[192][8];
    __shared__ float X1T[3][256][8];
    __shared__ float G[8][64];
    int t = threadIdx.x;
    int n0 = blockIdx.x*8;
    for (int idx=t; idx<2048; idx+=256){
        int nb = idx>>8, c = idx&255;
        float v = st[(n0+nb)*256 + c];
        if (c<32)       X0T[c][nb]=v;
        else if (c<64)  X0T[96+(c-32)][nb]=v;
        else if (c<160){ int cc=c-64;  X1T[cc%3][cc/3][nb]=v; }
        else           { int cc=c-160; X1T[cc%3][128+cc/3][nb]=v; }
    }
    for (int idx=t; idx<5632; idx+=256){
        int nb = idx/704, o = idx%704;
        float v = nbuf[(n0+nb)*704 + o];
        if (o<64)       X0T[32+o][nb]=v;
        else if (o<128) X0T[128+(o-64)][nb]=v;
        else if (o<416){ int oo=o-128; X1T[oo/96][32+(oo%96)][nb]=v; }
        else           { int oo=o-416; X1T[oo/96][160+(oo%96)][nb]=v; }
    }
    __syncthreads();
    {
        int c = t & 127, h = t >> 7;
        float a0=0.f,a1=0.f,a2=0.f,a3=0.f;
        int qb = (c<32) ? 0 : 96;
        #pragma unroll 4
        for (int r=0;r<96;r++){
            float w = W0[r*128+c];
            const float* xp = &X0T[qb+r][h*4];
            a0 += w*xp[0]; a1 += w*xp[1]; a2 += w*xp[2]; a3 += w*xp[3];
        }
        float accs[4]={a0,a1,a2,a3};
        #pragma unroll
        for (int j=0;j<4;j++){
            int nb = h*4+j, n = n0+nb;
            float o = accs[j];
            if (c<32)       stnew[n*256+c] = tanhf(o);
            else if (c<64)  stnew[n*256+c] = o*sigmoid_f(o);
            else            G[nb][c-64] = sigmoid_f(o);
        }
    }
    __syncthreads();
    int c2 = t & 63, w = t >> 6;
    if (w < 3){
        float acc[8];
        #pragma unroll
        for(int j=0;j<8;j++) acc[j]=0.f;
        int qb = (c2<32) ? 0 : 128;
        #pragma unroll 2
        for (int r=0;r<128;r++){
            float wt = W1[r*64+c2];
            const float* xp = &X1T[w][qb+r][0];
            #pragma unroll
            for(int j=0;j<8;j++) acc[j] += wt*xp[j];
        }
        int base = (c2<32) ? 64 + c2*3 + w : 160 + (c2-32)*3 + w;
        #pragma unroll
        for(int j=0;j<8;j++)
            stnew[(n0+j)*256 + base] = acc[j]*G[j][c2];
    }
}

// ---------------- final: node linears -> afin planes + per-node skip scalar (NO atomics) ----------
__global__ __launch_bounds__(128) void k_flin(const float* __restrict__ st,
    const float* __restrict__ wse, const float* __restrict__ wvo,
    const float* __restrict__ fsc_se,
    float* __restrict__ afin, float* __restrict__ sk)
{
    int n = blockIdx.x, t = threadIdx.x;
    const float* sr = st + n*256;
    float acc = 0.0f;
    if (t < 32){
        #pragma unroll
        for(int u=0;u<32;u++) acc += sr[32+u]*wse[u*32+t];
    } else {
        int idx=t-32, i=idx>>5, v=idx&31;
        #pragma unroll
        for(int u=0;u<32;u++) acc += sr[64+u*3+i]*wvo[u*32+v];
    }
    afin[n*128 + t] = acc * INV_S32;
    if (t < 32){
        float v = sr[32+t]*fsc_se[t];
        #pragma unroll
        for(int o=16;o>0;o>>=1) v += __shfl_xor(v, o);
        if (t==0) sk[n] = v * (C_S_F*INV_S32*OUT_S);
    }
}

// ---------------- final aggregate: EDGE-parallel, per-block partials (NO global atomics) ----------
__global__ __launch_bounds__(256) void k_fagg(const float* __restrict__ afin,
    const ushort* __restrict__ Wf2, const int* __restrict__ esrcs,
    const float4* __restrict__ ygeo, const int* __restrict__ gbs,
    const float* __restrict__ flin2, float* __restrict__ fpart)
{
    __shared__ float s_g[16];
    int t = threadIdx.x;
    if (t < 16) s_g[t] = 0.0f;
    __syncthreads();
    int u = t & 31, half = (t>>5)&1, w = t >> 6;
    const float FACT = C_X_F*0.125f*INV_SQ2*0.25f*OUT_S;
    float fl0 = flin2[u], fl1 = flin2[32+u];
    int base = (blockIdx.x*4 + w)*64;
    #pragma unroll 2
    for(int it=0; it<32; it++){
        int idx = base + it*2 + half;
        int s = esrcs[idx];
        float4 yg = ygeo[idx];
        const float* Ar = afin + s*128;
        float ase = Ar[u];
        float vx=Ar[32+u], vy=Ar[64+u], vz=Ar[96+u];
        uint p01 = *((const uint*)(Wf2 + (size_t)idx*64 + u*2));
        float w0 = bf2f((ushort)p01), w1 = bf2f((ushort)(p01>>16));
        float val = fl0*w0*ase*yg.x + fl1*w1*((vx*yg.y+vy*yg.z+vz*yg.w)*INV_SQ3);
        #pragma unroll
        for(int o=16;o>0;o>>=1) val += __shfl_xor(val, o);
        if (u==0) atomicAdd(&s_g[gbs[idx]], val*FACT);
    }
    __syncthreads();
    if (t < 16) fpart[blockIdx.x*16 + t] = s_g[t];
}

// ---------------- final reduction: sk + fpart -> out[16] --------
__global__ __launch_bounds__(256) void k_final(const float* __restrict__ sk,
    const int* __restrict__ batch, const float* __restrict__ fpart,
    float* __restrict__ out)
{
    __shared__ float bins[16];
    int t = threadIdx.x, b = blockIdx.x;     // 64 blocks
    if (t < 16) bins[t] = 0.0f;
    __syncthreads();
    if (t < 128){
        int n = b*128 + t;
        atomicAdd(&bins[batch[n]], sk[n]);
    } else {
        int i = b*128 + (t-128);             // fpart has 8192 entries
        atomicAdd(&bins[i & 15], fpart[i]);
    }
    __syncthreads();
    if (t < 16) atomicAdd(&out[t], bins[t]);
}

// ---------------- host ----------------
extern "C" void kernel_launch(void* const* d_in, const int* in_sizes, int n_in,
                              void* d_out, int out_size, void* d_ws, size_t ws_size,
                              hipStream_t stream)
{
    const float* x        = (const float*)d_in[0];
    const float* edge_vec = (const float*)d_in[1];
    const float* lin1_so  = (const float*)d_in[2];
    const float* lin1_se  = (const float*)d_in[3];
    const float* lin1_vo  = (const float*)d_in[4];
    const float* lin1_ve  = (const float*)d_in[5];
    const float* sc_so    = (const float*)d_in[6];
    const float* sc_se    = (const float*)d_in[7];
    const float* sc_vo    = (const float*)d_in[8];
    const float* sc_ve    = (const float*)d_in[9];
    const float* rad_w1   = (const float*)d_in[10];
    const float* rad_w2   = (const float*)d_in[11];
    const float* lin2_so  = (const float*)d_in[12];
    const float* lin2_se  = (const float*)d_in[13];
    const float* lin2_vo  = (const float*)d_in[14];
    const float* lin2_ve  = (const float*)d_in[15];
    const float* flin1_se = (const float*)d_in[16];
    const float* flin1_vo = (const float*)d_in[17];
    const float* fsc_se   = (const float*)d_in[18];
    const float* frad_w1  = (const float*)d_in[19];
    const float* frad_w2  = (const float*)d_in[20];
    const float* flin2    = (const float*)d_in[21];
    const int*   esrc     = (const int*)d_in[22];
    const int*   edst     = (const int*)d_in[23];
    const int*   batch    = (const int*)d_in[24];
    float* out = (float*)d_out;

    uint8_t* ws = (uint8_t*)d_ws;
    size_t off = 0;
    auto alloc = [&](size_t bytes)->void* {
        void* p = ws + off;
        off += (bytes + 255) & ~(size_t)255;
        return p;
    };
    float4* ygeo = (float4*)alloc((size_t)EE*16);
    float* embs  = (float*)alloc((size_t)EE*40);
    int*   esrcs = (int*)  alloc((size_t)EE*4);
    int*   gbs   = (int*)  alloc((size_t)EE*4);
    int*   cnt   = (int*)  alloc((size_t)NN*4);
    int*   csro  = (int*)  alloc((size_t)(NN+1)*4);
    int*   cur   = (int*)  alloc((size_t)NN*4);
    int*   eids  = (int*)  alloc((size_t)EE*4);
    uint*  Abf   = (uint*) alloc((size_t)NN*128*4);
    ushort* W    = (ushort*)alloc((size_t)EE*64*2);
    ushort* Bfrag3=(ushort*)alloc((size_t)3*40960*2);
    ushort* BfragF=(ushort*)alloc((size_t)8192*2);
    float* Wcat0 = (float*)alloc((size_t)3*12288*4);
    float* Wcat1 = (float*)alloc((size_t)3*8192*4);
    float* nbuf  = (float*)alloc((size_t)NN*704*4);
    float* st0   = (float*)alloc((size_t)NN*256*4);
    float* st1   = (float*)alloc((size_t)NN*256*4);
    float* afin  = (float*)alloc((size_t)NN*128*4);
    float* sk    = (float*)alloc((size_t)NN*4);
    float* fpart = (float*)alloc((size_t)512*16*4);

    hipMemsetAsync(out, 0, (size_t)out_size*sizeof(float), stream);
    hipMemsetAsync(cnt, 0, (size_t)NN*4, stream);

    k_count  <<<EE/256, 256, 0, stream>>>(edst, cnt);
    k_scan   <<<1, 1024, 0, stream>>>(cnt, csro, cur);
    k_scatter<<<EE/256, 256, 0, stream>>>(edst, cur, eids);
    k_geom_sorted<<<EE/256, 256, 0, stream>>>(edge_vec, eids, esrc, edst, batch,
                                              ygeo, embs, esrcs, gbs);
    k_prep3<<<480, 256, 0, stream>>>(rad_w2, Bfrag3);
    k_prep64<<<32, 256, 0, stream>>>(frad_w2, BfragF);
    k_prepu<<<240, 256, 0, stream>>>(sc_so, sc_se, sc_vo, sc_ve,
                                     lin2_so, lin2_se, lin2_vo, lin2_ve, Wcat0, Wcat1);

    const float* st_in = x;
    float* bufs[2] = { st0, st1 };
    const int NBLK = (NN + 2) / 3;   // 2731 blocks of 3 nodes
    for (int l=0; l<3; l++){
        k_lin1<<<NN/8, 256, 0, stream>>>(st_in,
            lin1_so + l*1024, lin1_se + l*1024, lin1_vo + l*1024, lin1_ve + l*1024, Abf);
        k_radagg<<<NBLK, 256, 0, stream>>>(embs, rad_w1 + l*1000, Bfrag3 + l*40960,
                                           Abf, ygeo, csro, esrcs, nbuf);
        float* st_out = bufs[l & 1];
        k_update<<<NN/8, 256, 0, stream>>>(st_in, nbuf, Wcat0 + l*12288, Wcat1 + l*8192, st_out);
        st_in = st_out;
    }
    k_flin<<<NN, 128, 0, stream>>>(st_in, flin1_se, flin1_vo, fsc_se, afin, sk);
    k_radial_mfma<64><<<EE/64, 256, 0, stream>>>(embs, frad_w1, BfragF, W);
    k_fagg<<<512, 256, 0, stream>>>(afin, W, esrcs, ygeo, gbs, flin2, fpart);
    k_final<<<64, 256, 0, stream>>>(sk, batch, fpart, out);
}

// Round 17
// 530.134 us; speedup vs baseline: 1.5052x; 1.5052x over previous
//
#include <hip/hip_runtime.h>
#include <hip/hip_bf16.h>
#include <math.h>
#include <string.h>
#include <stdint.h>

#define NN 8192
#define EE 131072

#define PI_F     3.14159265358979323846f
#define SQRT3_F  1.7320508075688772f
#define INV_SQ2  0.7071067811865476f
#define INV_SQ3  0.5773502691896258f
#define INV_S32  0.17677669529663687f
#define INV_S96  0.10206207261596575f
#define INV_S10  0.31622776601683794f
#define C_S_F    0.3826834323650898f
#define C_X_F    0.9238795325112867f
#define EMB_S    2.8234621965789795f   /* sqrt(10)/1.12 */
#define OUT_S    0.044194173824159216f /* 1/sqrt(512)   */

typedef unsigned int uint;
typedef unsigned short ushort;
typedef unsigned long long u64;
typedef __attribute__((ext_vector_type(8))) short short8;
typedef __attribute__((ext_vector_type(4))) float float4v;

__device__ __forceinline__ float sigmoid_f(float x){ return 1.0f/(1.0f+__expf(-x)); }
__device__ __forceinline__ ushort f2bf(float f){
    uint u = __float_as_uint(f);
    u = (u + 0x7fffu + ((u>>16)&1u)) >> 16;
    return (ushort)u;
}
__device__ __forceinline__ float bf2f(ushort w){ return __uint_as_float(((uint)w)<<16); }
__device__ __forceinline__ uint pk2bf(float a, float b){
    __hip_bfloat162 h = __float22bfloat162_rn(make_float2(a,b));   // v_cvt_pk_bf16_f32 (RNE)
    uint u; memcpy(&u,&h,4); return u;
}

// ---------------- CSR build (sort edges by dst) ----------------
__global__ __launch_bounds__(256) void k_count(const int* __restrict__ dst, int* __restrict__ cnt)
{
    int e = blockIdx.x*256 + threadIdx.x;
    atomicAdd(&cnt[dst[e]], 1);
}

__global__ __launch_bounds__(1024) void k_scan(const int* __restrict__ cnt,
    int* __restrict__ off, int* __restrict__ cur)
{
    __shared__ int partial[1024];
    int t = threadIdx.x;
    int base = t*8;
    int local[8];
    int s = 0;
    #pragma unroll
    for(int i=0;i<8;i++){ local[i]=s; s += cnt[base+i]; }
    partial[t] = s;
    __syncthreads();
    for(int d=1; d<1024; d<<=1){
        int v = (t>=d) ? partial[t-d] : 0;
        __syncthreads();
        partial[t] += v;
        __syncthreads();
    }
    int pref = (t>0) ? partial[t-1] : 0;
    #pragma unroll
    for(int i=0;i<8;i++){
        int o = pref + local[i];
        off[base+i] = o; cur[base+i] = o;
    }
    if (t==1023) off[NN] = partial[1023];
}

__global__ __launch_bounds__(256) void k_scatter(const int* __restrict__ dst,
    int* __restrict__ cur, int* __restrict__ eids)
{
    int e = blockIdx.x*256 + threadIdx.x;
    int p = atomicAdd(&cur[dst[e]], 1);
    eids[p] = e;
}

// ---------------- edge geometry in CSR-sorted order; ygeo = (y0, y1x, y1y, y1z) float4 ----------
__global__ __launch_bounds__(256) void k_geom_sorted(const float* __restrict__ ev,
    const int* __restrict__ eids, const int* __restrict__ esrc,
    const int* __restrict__ edst, const int* __restrict__ batch,
    float4* __restrict__ ygeo, float* __restrict__ embs,
    int* __restrict__ esrcs, int* __restrict__ gbs)
{
    int p = blockIdx.x*256 + threadIdx.x;
    int e = eids[p];
    float vx=ev[e*3+0], vy=ev[e*3+1], vz=ev[e*3+2];
    float r = sqrtf(vx*vx+vy*vy+vz*vz);
    float uu = 0.5f*r - 2.0f;                 // u = 2*(r/4 - 1)
    float cut;
    if (uu > 0.0f)       cut = 0.0f;
    else if (uu < -1.0f) cut = 1.0f;
    else                 cut = 0.5f*(1.0f - cosf(PI_F*uu));
    float s = SQRT3_F*cut/(r + 1e-12f);
    ygeo[p] = make_float4(cut, vx*s, vy*s, vz*s);
    #pragma unroll
    for(int b=0;b<10;b++){
        float d = r*2.25f - (float)b;         // (r - b*4/9)/(4/9)
        embs[p*10+b] = __expf(-d*d)*EMB_S;
    }
    esrcs[p] = esrc[e];
    gbs[p]   = batch[edst[e]];
}

// ---------------- per-node input linears -> PACKED bf16 A planes ----------------
// Abf row (128 uints): q*32+u = bf16 pair (plane 2q, plane 2q+1) of channel u.
// Planes: 0=a_so 1=a_se 2=vo_x 3=vo_y 4=vo_z 5=ve_x 6=ve_y 7=ve_z.
__global__ __launch_bounds__(256) void k_lin1(const float* __restrict__ st,
    const float* __restrict__ w_so, const float* __restrict__ w_se,
    const float* __restrict__ w_vo, const float* __restrict__ w_ve,
    uint* __restrict__ Abf)
{
    __shared__ float wl[4][1024];
    __shared__ float sl[8][256];
    __shared__ float ol[8][256];
    int t = threadIdx.x;
    for(int i=t;i<1024;i+=256){ wl[0][i]=w_so[i]; wl[1][i]=w_se[i]; wl[2][i]=w_vo[i]; wl[3][i]=w_ve[i]; }
    int n0 = blockIdx.x*8;
    for(int i=t;i<2048;i+=256){ int k=i>>8, c=i&255; sl[k][c]=st[(n0+k)*256+c]; }
    __syncthreads();
    for(int k=0;k<8;k++){
        float acc = 0.0f;
        if (t < 64){
            int m = t>>5, v = t&31;
            const float* w = wl[m];
            const float* s = &sl[k][m*32];
            #pragma unroll
            for(int u=0;u<32;u++) acc += s[u]*w[u*32+v];
        } else if (t < 160){
            int idx=t-64, i=idx>>5, v=idx&31;
            #pragma unroll
            for(int u=0;u<32;u++) acc += sl[k][64+u*3+i]*wl[2][u*32+v];
        } else {
            int idx=t-160, i=idx>>5, v=idx&31;
            #pragma unroll
            for(int u=0;u<32;u++) acc += sl[k][160+u*3+i]*wl[3][u*32+v];
        }
        ol[k][t] = acc * INV_S32;
    }
    __syncthreads();
    for(int idx=t; idx<1024; idx+=256){
        int k = idx>>7, j = idx&127, q = j>>5, u = j&31;
        Abf[(size_t)(n0+k)*128 + j] = pk2bf(ol[k][q*64 + u], ol[k][q*64 + 32 + u]);
    }
}

// ---------------- rw2 fp32 -> bf16 fragment layout, PLANE-MAJOR packed order ----------
__global__ __launch_bounds__(256) void k_prep3(const float* __restrict__ rw2, ushort* __restrict__ Bfrag)
{
    int L = blockIdx.x / 160;
    int idx = (blockIdx.x % 160)*256 + threadIdx.x;      // over 128*320 elements
    int j = idx & 7;
    int l = (idx>>3) & 63;
    int rest = idx >> 9;                          // ks*20 + mt
    int nt = rest % 20;
    int ks = rest / 20;
    int k = ks*32 + ((l>>4)&3)*8 + j;
    int p = nt*16 + (l&15);
    int n = (2*(p>>6) + (p&1))*32 + ((p&63)>>1);  // plane-major packing
    float v = (k < 100) ? rw2[L*32000 + k*320 + n] : 0.0f;
    Bfrag[L*40960 + idx] = f2bf(v);
}

__global__ __launch_bounds__(256) void k_prep64(const float* __restrict__ rw2, ushort* __restrict__ Bfrag)
{
    int idx = blockIdx.x*256 + threadIdx.x;      // over 128*64 elements
    int j = idx & 7;
    int l = (idx>>3) & 63;
    int rest = idx >> 9;                          // ks*4 + mt
    int nt = rest % 4;
    int ks = rest / 4;
    int k = ks*32 + ((l>>4)&3)*8 + j;
    int p = nt*16 + (l&15);
    int n = (p % 2)*32 + p/2;
    float v = (k < 100) ? rw2[k*64 + n] : 0.0f;
    Bfrag[idx] = f2bf(v);
}

// ---------------- update-weight pre-pack: scales folded, dense, all 3 layers ----------------
__global__ __launch_bounds__(256) void k_prepu(
    const float* __restrict__ sc_so, const float* __restrict__ sc_se,
    const float* __restrict__ sc_vo, const float* __restrict__ sc_ve,
    const float* __restrict__ lin2_so, const float* __restrict__ lin2_se,
    const float* __restrict__ lin2_vo, const float* __restrict__ lin2_ve,
    float* __restrict__ Wcat0, float* __restrict__ Wcat1)
{
    int idx = blockIdx.x*256 + threadIdx.x;   // 3 layers x 20480
    int L = idx / 20480;
    int k = idx % 20480;
    const float CS32 = C_S_F*INV_S32, CX8 = C_X_F*0.125f, CX96 = C_X_F*INV_S96;
    if (k < 12288){
        int r = k >> 7, c = k & 127;
        float v;
        if (c < 32) v = (r<32) ? CS32*sc_so[L*1024 + r*32+c]        : CX8*lin2_so[L*2048 + (r-32)*32+c];
        else        v = (r<32) ? CS32*sc_se[L*3072 + r*96+(c-32)]   : CX8*lin2_se[L*6144 + (r-32)*96+(c-32)];
        Wcat0[L*12288 + k] = v;
    } else {
        int k2 = k - 12288;
        int r = k2 >> 6, c = k2 & 63;
        float v;
        if (c < 32) v = (r<32) ? CS32*sc_vo[L*1024 + r*32+c]        : CX96*lin2_vo[L*3072 + (r-32)*32+c];
        else        v = (r<32) ? CS32*sc_ve[L*1024 + r*32+(c-32)]   : CX96*lin2_ve[L*3072 + (r-32)*32+(c-32)];
        Wcat1[L*8192 + k2] = v;
    }
}

// ---------------- radial MLP via MFMA, FLIPPED: C[pos x edge] = RW2^T @ H^T ----------
// R11-proven structure: staged LDS C-stage + coalesced copy-out; readfirstlane-uniform phase 1.
template<int NCOL>
__global__ __launch_bounds__(256, 3) void k_radial_mfma(const float* __restrict__ emb,
    const float* __restrict__ rw1, const ushort* __restrict__ Afrag,
    ushort* __restrict__ Wout)
{
    constexpr int MTW = NCOL/64;            // M(pos)-tiles per wave: 320->5, 64->1
    constexpr int STR = NCOL + 8;           // stage row stride in ushorts (16B-aligned rows)
    constexpr int BIG = (64*STR > 8192) ? 64*STR : 8192;
    __shared__ __align__(16) ushort s_big[BIG];   // h-frag (16 KB) then reused as C-stage
    __shared__ float s_emb[640];
    int t = threadIdx.x;
    int ebase = blockIdx.x*64;
    for(int i=t;i<640;i+=256)  s_emb[i] = emb[ebase*10 + i];
    for(int i=t;i<1024;i+=256) ((uint*)s_big)[3072 + i] = 0u;
    __syncthreads();
    {   // phase 1: h = silu(emb@rw1/sqrt(10)), lane = edge, wave = k-slice (SGPR-uniform)
        int w4 = __builtin_amdgcn_readfirstlane(t) >> 6;   // SGPR wave index
        int l = t & 63;
        float ev[10];
        #pragma unroll
        for(int r=0;r<10;r++) ev[r] = s_emb[l*10 + r];
        int m  = l & 15, nt = l >> 4;
        int kbeg = w4*25;
        #pragma unroll 5
        for(int k=kbeg; k<kbeg+25; k++){
            float a0 = 0.0f;
            #pragma unroll
            for(int r=0;r<10;r++) a0 += ev[r]*rw1[r*100 + k];   // uniform addr -> s_load
            a0 *= INV_S10;
            float h = a0*sigmoid_f(a0);
            int ks = k >> 5, kk = k & 31;
            int lt = m | ((kk>>3)<<4);
            s_big[((ks*4 + nt)*64 + lt)*8 + (kk&7)] = f2bf(h);
        }
    }
    __syncthreads();
    // phase 2: MFMA — A = rw2^T frag (global, L2-hot), B = h frag (LDS)
    int w = t >> 6, l = t & 63;
    float4v acc[MTW][4];
    #pragma unroll
    for(int a=0;a<MTW;a++)
        #pragma unroll
        for(int b=0;b<4;b++)
            acc[a][b] = (float4v){0.f,0.f,0.f,0.f};
    #pragma unroll
    for(int ks=0;ks<4;ks++){
        short8 bfr[4];
        #pragma unroll
        for(int nt=0;nt<4;nt++)
            bfr[nt] = *((const short8*)&s_big[((ks*4+nt)*64 + l)*8]);
        #pragma unroll
        for(int mtl=0;mtl<MTW;mtl++){
            short8 af = *((const short8*)(Afrag + ((size_t)(ks*(NCOL/16) + w*MTW + mtl)*64 + l)*8));
            #pragma unroll
            for(int nt=0;nt<4;nt++)
                acc[mtl][nt] = __builtin_amdgcn_mfma_f32_16x16x32_bf16(af, bfr[nt], acc[mtl][nt], 0, 0, 0);
        }
    }
    __syncthreads();   // all h-frag reads done; reuse s_big as C-stage
    {
        int col16 = l & 15, rquad = l >> 4;
        #pragma unroll
        for(int mtl=0;mtl<MTW;mtl++){
            int pos0 = (w*MTW + mtl)*16 + rquad*4;
            #pragma unroll
            for(int nt=0;nt<4;nt++){
                int edge = nt*16 + col16;
                uint u01 = pk2bf(acc[mtl][nt][0]*0.1f, acc[mtl][nt][1]*0.1f);
                uint u23 = pk2bf(acc[mtl][nt][2]*0.1f, acc[mtl][nt][3]*0.1f);
                u64 pk = (u64)u01 | ((u64)u23 << 32);
                *((u64*)&s_big[edge*STR + pos0]) = pk;     // /sqrt(100) folded
            }
        }
    }
    __syncthreads();
    for (int idx = t; idx < 64*(NCOL/8); idx += 256){
        int row = idx/(NCOL/8), o8 = idx%(NCOL/8);
        short8 vv = *((const short8*)&s_big[row*STR + o8*8]);
        *((short8*)(Wout + (size_t)(ebase+row)*NCOL + o8*8)) = vv;
    }
}

// ---------------- per-node message aggregation: 1 wave/node, packed bf16 A + W planes + ygeo -----
// nbuf row (704): [n0o 64 | n0e 64 | n1o_x 96 | n1o_y 96 | n1o_z 96 | n1e_x 96 | n1e_y 96 | n1e_z 96]
__global__ __launch_bounds__(64) void k_aggregate(const uint* __restrict__ Abf,
    const ushort* __restrict__ W2, const float4* __restrict__ ygeo,
    const int* __restrict__ off, const int* __restrict__ esrcs,
    float* __restrict__ nbuf)
{
    int n = blockIdx.x;
    int l = threadIdx.x;
    int u = l & 31, half = l >> 5;
    int e0 = off[n], e1 = off[n+1];
    float a_n0o0=0.f, a_n0o1=0.f, a_n0e0=0.f, a_n0e1=0.f;
    float a1o[3][3] = {{0}}, a1e[3][3] = {{0}};
    #pragma unroll 2
    for(int p=e0;p<e1;p+=2){
        int idx = p + half;
        bool valid = idx < e1;
        int ic = valid ? idx : e0;          // clamp to a safe in-range slot
        int s = esrcs[ic];
        float4 yg = ygeo[ic];
        float cy0 = valid ? yg.x : 0.0f;
        float v1x = yg.y, v1y = yg.z, v1z = yg.w;
        if (!valid){ v1x=0.f; v1y=0.f; v1z=0.f; }
        const uint* Au = Abf + (size_t)s*128;
        uint a01=Au[u], a23=Au[32+u], a45=Au[64+u], a67=Au[96+u];
        float aso=bf2f((ushort)a01), ase=bf2f((ushort)(a01>>16));
        float vox=bf2f((ushort)a23), voy=bf2f((ushort)(a23>>16));
        float voz=bf2f((ushort)a45), vex=bf2f((ushort)(a45>>16));
        float vey=bf2f((ushort)a67), vez=bf2f((ushort)(a67>>16));
        const uint* Wu = (const uint*)(W2) + (size_t)ic*160;   // plane-major: coalesced
        uint p01=Wu[u], p23=Wu[32+u], p45=Wu[64+u], p67=Wu[96+u], p89=Wu[128+u];
        float w0=bf2f((ushort)p01), w1=bf2f((ushort)(p01>>16));
        float w2=bf2f((ushort)p23), w3=bf2f((ushort)(p23>>16));
        float w4=bf2f((ushort)p45), w5=bf2f((ushort)(p45>>16));
        float w6=bf2f((ushort)p67), w7=bf2f((ushort)(p67>>16));
        float w8=bf2f((ushort)p89), w9=bf2f((ushort)(p89>>16));
        float dve = (vex*v1x+vey*v1y+vez*v1z)*INV_SQ3;
        float dvo = (vox*v1x+voy*v1y+voz*v1z)*INV_SQ3;
        float cvex=(vey*v1z-vez*v1y)*INV_SQ2, cvey=(vez*v1x-vex*v1z)*INV_SQ2, cvez=(vex*v1y-vey*v1x)*INV_SQ2;
        float cvox=(voy*v1z-voz*v1y)*INV_SQ2, cvoy=(voz*v1x-vox*v1z)*INV_SQ2, cvoz=(vox*v1y-voy*v1x)*INV_SQ2;
        a_n0o0 += w0*aso*cy0;
        a_n0o1 += w1*dve;
        a_n0e0 += w2*ase*cy0;
        a_n0e1 += w3*dvo;
        a1o[0][0]+=w4*ase*v1x; a1o[0][1]+=w4*ase*v1y; a1o[0][2]+=w4*ase*v1z;
        a1o[1][0]+=w5*vox*cy0; a1o[1][1]+=w5*voy*cy0; a1o[1][2]+=w5*voz*cy0;
        a1o[2][0]+=w6*cvex;    a1o[2][1]+=w6*cvey;    a1o[2][2]+=w6*cvez;
        a1e[0][0]+=w7*aso*v1x; a1e[0][1]+=w7*aso*v1y; a1e[0][2]+=w7*aso*v1z;
        a1e[1][0]+=w8*cvox;    a1e[1][1]+=w8*cvoy;    a1e[1][2]+=w8*cvoz;
        a1e[2][0]+=w9*vex*cy0; a1e[2][1]+=w9*vey*cy0; a1e[2][2]+=w9*vez*cy0;
    }
    // combine the two half-wave edge partitions
    a_n0o0 += __shfl_xor(a_n0o0, 32);
    a_n0o1 += __shfl_xor(a_n0o1, 32);
    a_n0e0 += __shfl_xor(a_n0e0, 32);
    a_n0e1 += __shfl_xor(a_n0e1, 32);
    #pragma unroll
    for(int sp=0;sp<3;sp++)
        #pragma unroll
        for(int i=0;i<3;i++){
            a1o[sp][i] += __shfl_xor(a1o[sp][i], 32);
            a1e[sp][i] += __shfl_xor(a1e[sp][i], 32);
        }
    float s0 = INV_SQ2*0.25f;   // m0 concat scale * seg 1/sqrt(16)
    float s1 = INV_SQ3*0.25f;   // m1 concat scale * seg
    float* nb = nbuf + n*704;
    if (half==0){
        nb[u]      = a_n0o0*s0;
        nb[32+u]   = a_n0o1*s0;
        nb[64+u]   = a_n0e0*s0;
        nb[96+u]   = a_n0e1*s0;
        #pragma unroll
        for(int sp=0;sp<3;sp++)
            #pragma unroll
            for(int i=0;i<3;i++)
                nb[128 + i*96 + sp*32 + u] = a1o[sp][i]*s1;
    } else {
        #pragma unroll
        for(int sp=0;sp<3;sp++)
            #pragma unroll
            for(int i=0;i<3;i++)
                nb[416 + i*96 + sp*32 + u] = a1e[sp][i]*s1;
    }
}

// ---------------- node update: 8 nodes/block, LDS-transposed inputs, packed weights ---
__global__ __launch_bounds__(256, 4) void k_update(const float* __restrict__ st,
    const float* __restrict__ nbuf, const float* __restrict__ W0,
    const float* __restrict__ W1, float* __restrict__ stnew)
{
    __shared__ float X0T[192][8];
    __shared__ float X1T[3][256][8];
    __shared__ float G[8][64];
    int t = threadIdx.x;
    int n0 = blockIdx.x*8;
    for (int idx=t; idx<2048; idx+=256){
        int nb = idx>>8, c = idx&255;
        float v = st[(n0+nb)*256 + c];
        if (c<32)       X0T[c][nb]=v;
        else if (c<64)  X0T[96+(c-32)][nb]=v;
        else if (c<160){ int cc=c-64;  X1T[cc%3][cc/3][nb]=v; }
        else           { int cc=c-160; X1T[cc%3][128+cc/3][nb]=v; }
    }
    for (int idx=t; idx<5632; idx+=256){
        int nb = idx/704, o = idx%704;
        float v = nbuf[(n0+nb)*704 + o];
        if (o<64)       X0T[32+o][nb]=v;
        else if (o<128) X0T[128+(o-64)][nb]=v;
        else if (o<416){ int oo=o-128; X1T[oo/96][32+(oo%96)][nb]=v; }
        else           { int oo=o-416; X1T[oo/96][160+(oo%96)][nb]=v; }
    }
    __syncthreads();
    {
        int c = t & 127, h = t >> 7;
        float a0=0.f,a1=0.f,a2=0.f,a3=0.f;
        int qb = (c<32) ? 0 : 96;
        #pragma unroll 4
        for (int r=0;r<96;r++){
            float w = W0[r*128+c];
            const float* xp = &X0T[qb+r][h*4];
            a0 += w*xp[0]; a1 += w*xp[1]; a2 += w*xp[2]; a3 += w*xp[3];
        }
        float accs[4]={a0,a1,a2,a3};
        #pragma unroll
        for (int j=0;j<4;j++){
            int nb = h*4+j, n = n0+nb;
            float o = accs[j];
            if (c<32)       stnew[n*256+c] = tanhf(o);
            else if (c<64)  stnew[n*256+c] = o*sigmoid_f(o);
            else            G[nb][c-64] = sigmoid_f(o);
        }
    }
    __syncthreads();
    int c2 = t & 63, w = t >> 6;
    if (w < 3){
        float acc[8];
        #pragma unroll
        for(int j=0;j<8;j++) acc[j]=0.f;
        int qb = (c2<32) ? 0 : 128;
        #pragma unroll 2
        for (int r=0;r<128;r++){
            float wt = W1[r*64+c2];
            const float* xp = &X1T[w][qb+r][0];
            #pragma unroll
            for(int j=0;j<8;j++) acc[j] += wt*xp[j];
        }
        int base = (c2<32) ? 64 + c2*3 + w : 160 + (c2-32)*3 + w;
        #pragma unroll
        for(int j=0;j<8;j++)
            stnew[(n0+j)*256 + base] = acc[j]*G[j][c2];
    }
}

// ---------------- final: node linears -> afin planes + per-node skip scalar (NO atomics) ----------
__global__ __launch_bounds__(128) void k_flin(const float* __restrict__ st,
    const float* __restrict__ wse, const float* __restrict__ wvo,
    const float* __restrict__ fsc_se,
    float* __restrict__ afin, float* __restrict__ sk)
{
    int n = blockIdx.x, t = threadIdx.x;
    const float* sr = st + n*256;
    float acc = 0.0f;
    if (t < 32){
        #pragma unroll
        for(int u=0;u<32;u++) acc += sr[32+u]*wse[u*32+t];
    } else {
        int idx=t-32, i=idx>>5, v=idx&31;
        #pragma unroll
        for(int u=0;u<32;u++) acc += sr[64+u*3+i]*wvo[u*32+v];
    }
    afin[n*128 + t] = acc * INV_S32;
    if (t < 32){
        float v = sr[32+t]*fsc_se[t];
        #pragma unroll
        for(int o=16;o>0;o>>=1) v += __shfl_xor(v, o);
        if (t==0) sk[n] = v * (C_S_F*INV_S32*OUT_S);
    }
}

// ---------------- final aggregate: EDGE-parallel, per-block partials (NO global atomics) ----------
__global__ __launch_bounds__(256) void k_fagg(const float* __restrict__ afin,
    const ushort* __restrict__ Wf2, const int* __restrict__ esrcs,
    const float4* __restrict__ ygeo, const int* __restrict__ gbs,
    const float* __restrict__ flin2, float* __restrict__ fpart)
{
    __shared__ float s_g[16];
    int t = threadIdx.x;
    if (t < 16) s_g[t] = 0.0f;
    __syncthreads();
    int u = t & 31, half = (t>>5)&1, w = t >> 6;
    const float FACT = C_X_F*0.125f*INV_SQ2*0.25f*OUT_S;
    float fl0 = flin2[u], fl1 = flin2[32+u];
    int base = (blockIdx.x*4 + w)*64;
    #pragma unroll 2
    for(int it=0; it<32; it++){
        int idx = base + it*2 + half;
        int s = esrcs[idx];
        float4 yg = ygeo[idx];
        const float* Ar = afin + s*128;
        float ase = Ar[u];
        float vx=Ar[32+u], vy=Ar[64+u], vz=Ar[96+u];
        uint p01 = *((const uint*)(Wf2 + (size_t)idx*64 + u*2));
        float w0 = bf2f((ushort)p01), w1 = bf2f((ushort)(p01>>16));
        float val = fl0*w0*ase*yg.x + fl1*w1*((vx*yg.y+vy*yg.z+vz*yg.w)*INV_SQ3);
        #pragma unroll
        for(int o=16;o>0;o>>=1) val += __shfl_xor(val, o);
        if (u==0) atomicAdd(&s_g[gbs[idx]], val*FACT);
    }
    __syncthreads();
    if (t < 16) fpart[blockIdx.x*16 + t] = s_g[t];
}

// ---------------- final reduction: sk + fpart -> out[16] --------
__global__ __launch_bounds__(256) void k_final(const float* __restrict__ sk,
    const int* __restrict__ batch, const float* __restrict__ fpart,
    float* __restrict__ out)
{
    __shared__ float bins[16];
    int t = threadIdx.x, b = blockIdx.x;     // 64 blocks
    if (t < 16) bins[t] = 0.0f;
    __syncthreads();
    if (t < 128){
        int n = b*128 + t;
        atomicAdd(&bins[batch[n]], sk[n]);
    } else {
        int i = b*128 + (t-128);             // fpart has 8192 entries
        atomicAdd(&bins[i & 15], fpart[i]);
    }
    __syncthreads();
    if (t < 16) atomicAdd(&out[t], bins[t]);
}

// ---------------- host ----------------
extern "C" void kernel_launch(void* const* d_in, const int* in_sizes, int n_in,
                              void* d_out, int out_size, void* d_ws, size_t ws_size,
                              hipStream_t stream)
{
    const float* x        = (const float*)d_in[0];
    const float* edge_vec = (const float*)d_in[1];
    const float* lin1_so  = (const float*)d_in[2];
    const float* lin1_se  = (const float*)d_in[3];
    const float* lin1_vo  = (const float*)d_in[4];
    const float* lin1_ve  = (const float*)d_in[5];
    const float* sc_so    = (const float*)d_in[6];
    const float* sc_se    = (const float*)d_in[7];
    const float* sc_vo    = (const float*)d_in[8];
    const float* sc_ve    = (const float*)d_in[9];
    const float* rad_w1   = (const float*)d_in[10];
    const float* rad_w2   = (const float*)d_in[11];
    const float* lin2_so  = (const float*)d_in[12];
    const float* lin2_se  = (const float*)d_in[13];
    const float* lin2_vo  = (const float*)d_in[14];
    const float* lin2_ve  = (const float*)d_in[15];
    const float* flin1_se = (const float*)d_in[16];
    const float* flin1_vo = (const float*)d_in[17];
    const float* fsc_se   = (const float*)d_in[18];
    const float* frad_w1  = (const float*)d_in[19];
    const float* frad_w2  = (const float*)d_in[20];
    const float* flin2    = (const float*)d_in[21];
    const int*   esrc     = (const int*)d_in[22];
    const int*   edst     = (const int*)d_in[23];
    const int*   batch    = (const int*)d_in[24];
    float* out = (float*)d_out;

    uint8_t* ws = (uint8_t*)d_ws;
    size_t off = 0;
    auto alloc = [&](size_t bytes)->void* {
        void* p = ws + off;
        off += (bytes + 255) & ~(size_t)255;
        return p;
    };
    float4* ygeo = (float4*)alloc((size_t)EE*16);
    float* embs  = (float*)alloc((size_t)EE*40);
    int*   esrcs = (int*)  alloc((size_t)EE*4);
    int*   gbs   = (int*)  alloc((size_t)EE*4);
    int*   cnt   = (int*)  alloc((size_t)NN*4);
    int*   csro  = (int*)  alloc((size_t)(NN+1)*4);
    int*   cur   = (int*)  alloc((size_t)NN*4);
    int*   eids  = (int*)  alloc((size_t)EE*4);
    uint*  Abf   = (uint*) alloc((size_t)NN*128*4);
    ushort* W    = (ushort*)alloc((size_t)EE*320*2);
    ushort* Bfrag3=(ushort*)alloc((size_t)3*40960*2);
    ushort* BfragF=(ushort*)alloc((size_t)8192*2);
    float* Wcat0 = (float*)alloc((size_t)3*12288*4);
    float* Wcat1 = (float*)alloc((size_t)3*8192*4);
    float* nbuf  = (float*)alloc((size_t)NN*704*4);
    float* st0   = (float*)alloc((size_t)NN*256*4);
    float* st1   = (float*)alloc((size_t)NN*256*4);
    float* afin  = (float*)alloc((size_t)NN*128*4);
    float* sk    = (float*)alloc((size_t)NN*4);
    float* fpart = (float*)alloc((size_t)512*16*4);

    hipMemsetAsync(out, 0, (size_t)out_size*sizeof(float), stream);
    hipMemsetAsync(cnt, 0, (size_t)NN*4, stream);

    k_count  <<<EE/256, 256, 0, stream>>>(edst, cnt);
    k_scan   <<<1, 1024, 0, stream>>>(cnt, csro, cur);
    k_scatter<<<EE/256, 256, 0, stream>>>(edst, cur, eids);
    k_geom_sorted<<<EE/256, 256, 0, stream>>>(edge_vec, eids, esrc, edst, batch,
                                              ygeo, embs, esrcs, gbs);
    k_prep3<<<480, 256, 0, stream>>>(rad_w2, Bfrag3);
    k_prep64<<<32, 256, 0, stream>>>(frad_w2, BfragF);
    k_prepu<<<240, 256, 0, stream>>>(sc_so, sc_se, sc_vo, sc_ve,
                                     lin2_so, lin2_se, lin2_vo, lin2_ve, Wcat0, Wcat1);

    const float* st_in = x;
    float* bufs[2] = { st0, st1 };
    for (int l=0; l<3; l++){
        k_lin1<<<NN/8, 256, 0, stream>>>(st_in,
            lin1_so + l*1024, lin1_se + l*1024, lin1_vo + l*1024, lin1_ve + l*1024, Abf);
        k_radial_mfma<320><<<EE/64, 256, 0, stream>>>(embs, rad_w1 + l*1000, Bfrag3 + l*40960, W);
        k_aggregate<<<NN, 64, 0, stream>>>(Abf, W, ygeo, csro, esrcs, nbuf);
        float* st_out = bufs[l & 1];
        k_update<<<NN/8, 256, 0, stream>>>(st_in, nbuf, Wcat0 + l*12288, Wcat1 + l*8192, st_out);
        st_in = st_out;
    }
    k_flin<<<NN, 128, 0, stream>>>(st_in, flin1_se, flin1_vo, fsc_se, afin, sk);
    k_radial_mfma<64><<<EE/64, 256, 0, stream>>>(embs, frad_w1, BfragF, W);
    k_fagg<<<512, 256, 0, stream>>>(afin, W, esrcs, ygeo, gbs, flin2, fpart);
    k_final<<<64, 256, 0, stream>>>(sk, batch, fpart, out);
}